// Round 14
// baseline (582.407 us; speedup 1.0000x reference)
//
#include <hip/hip_runtime.h>
#include <hip/hip_bf16.h>
#include <math.h>

typedef unsigned short ushort_t;
typedef unsigned long long u64;
typedef __bf16 bf16x8 __attribute__((ext_vector_type(8)));
typedef float f32x4 __attribute__((ext_vector_type(4)));

#define BB 128
#define TT 24
#define EE 512
#define VV 30000
#define HH 1024
#define GG 4096
#define MM (BB*TT)   // 3072 rows, m = t*128 + b
#define MPAD 30208   // 118 tiles of 256

static __device__ __forceinline__ ushort_t f2bf(float x) {
  __hip_bfloat16 h = __float2bfloat16(x);
  return __builtin_bit_cast(ushort_t, h);
}

// async global->LDS, 16B per lane; lds base must be wave-uniform
static __device__ __forceinline__ void gld_lds16(const void* g, void* l) {
  __builtin_amdgcn_global_load_lds((const __attribute__((address_space(1))) void*)g,
                                   (__attribute__((address_space(3))) void*)l, 16, 0, 0);
}

// ---------------- fused prep: 3 bf16 casts + bias sum ----------------
__global__ void prep_k(const float* __restrict__ Wih, const float* __restrict__ Whh,
                       const float* __restrict__ Wout,
                       const float* __restrict__ bi, const float* __restrict__ bh,
                       ushort_t* __restrict__ Wih_b, ushort_t* __restrict__ Whh_b,
                       ushort_t* __restrict__ Wout_b, float* __restrict__ bs) {
  const int bid = blockIdx.x, tid = threadIdx.x;
  const float* s; ushort_t* d; int n4, i0, stride;
  if (bid < 2048) {        // Wout: 7.68M float4
    s = Wout; d = Wout_b; n4 = VV * HH / 4; i0 = bid * 256 + tid; stride = 2048 * 256;
  } else if (bid < 2560) { // Wih
    s = Wih; d = Wih_b; n4 = GG * HH / 4; i0 = (bid - 2048) * 256 + tid; stride = 512 * 256;
  } else if (bid < 3072) { // Whh
    s = Whh; d = Whh_b; n4 = GG * HH / 4; i0 = (bid - 2560) * 256 + tid; stride = 512 * 256;
  } else {                 // bias
    for (int i = tid; i < GG; i += 256) bs[i] = bi[i] + bh[i];
    return;
  }
  for (int i = i0; i < n4; i += stride) {
    float4 v = reinterpret_cast<const float4*>(s)[i];
    ushort4 o;
    o.x = f2bf(v.x); o.y = f2bf(v.y); o.z = f2bf(v.z); o.w = f2bf(v.w);
    reinterpret_cast<ushort4*>(d)[i] = o;
  }
}

__global__ void build_xa_k(const float* __restrict__ emb, const int* __restrict__ captions,
                           const int* __restrict__ pad_idx, const float* __restrict__ features,
                           ushort_t* __restrict__ xa) {
  int row = blockIdx.x;          // 0..3071, row = t*128+b
  int t = row >> 7;
  int b = row & 127;
  int cap = (t == 0) ? pad_idx[0] : captions[b * TT + (t - 1)];
  const float* s0 = emb + (size_t)cap * EE;
  const float* s1 = features + (size_t)b * EE;
  ushort_t* d = xa + (size_t)row * (2 * EE);
  for (int e = threadIdx.x; e < EE; e += 256) {
    d[e] = f2bf(s0[e]);
    d[EE + e] = f2bf(s1[e]);
  }
}

__global__ void zero_bar_k(int* __restrict__ bar) {
  for (int i = threadIdx.x; i < 4096; i += 256)
    __hip_atomic_store(&bar[i], 0, __ATOMIC_RELAXED, __HIP_MEMORY_SCOPE_AGENT);
}

// ---------------- GEMM 256x256, 4-phase/K-tile, MINIMAL barriers ----------------
// Hazard analysis: within a tile all phases READ buf (landed) and DMA-WRITE bufn
// (not read until next tile). Required cross-wave publish points only:
//   after Ph1: B1(g) landed (vmcnt(4)+barrier)   [Ph2 reads B1]
//   after Ph2: A1(g) landed (vmcnt(4)+barrier)   [Ph3 reads A1]
//   after Ph4: A0',B0' landed (vmcnt(4)+barrier) [next Ph1 reads them; also ensures
//              all waves finished reading buf before it is re-staged next tile]
// No intra-phase lgkmcnt(0)/sched_barrier: compiler emits counted lgkmcnt per MFMA
// operand; waves drift so one wave's ds_reads overlap another's MFMAs.
// MODE 1 (logits): A=Wout_b[30208], B=hs[3072]; grid 1416 = 8x177.
// MODE 0 (xg):     A=xa[3072],      B=Wih_b[4096]; grid 192 = 8x24.
template<int MODE>
__global__ __launch_bounds__(512) void gemm256(
    const ushort_t* __restrict__ A,
    const ushort_t* __restrict__ Bm,
    const float* __restrict__ bias,
    float* __restrict__ out)
{
  constexpr int K = 1024, NT = 16;
  __shared__ __align__(16) ushort_t As[2][16384];
  __shared__ __align__(16) ushort_t Bs[2][16384];
  const int bid = blockIdx.x;
  int m0, n0;
  if (MODE == 1) {
    const int g = (bid & 7) * 177 + (bid >> 3);     // XCD-contiguous tiles
    m0 = (g / 12) * 256; n0 = (g % 12) * 256;
  } else {
    const int c = bid >> 3;                         // 0..23
    m0 = (c % 12) * 256; n0 = ((bid & 7) * 2 + c / 12) * 256;
  }
  const int tid = threadIdx.x, wid = tid >> 6, lane = tid & 63;
  const int wm2 = wid >> 2, wn4 = wid & 3;
  const int rr = lane & 15, l4 = lane >> 4;

  f32x4 acc[8][4] = {};   // [mf 0..7][nf 0..3]

  auto stage = [&](int buf, int kt, int ct) {
    const int k0 = kt * 64;
    #pragma unroll
    for (int l = 0; l < 2; ++l) {
      int f = l * 512 + tid;
      int lr = f >> 3;
      int ecol = k0 + (((f & 7) ^ (lr & 7)) * 8);
      if (ct == 0 || ct == 3) {
        int cc = (ct == 3);
        int grow = (lr & 63) + ((lr >> 6) << 7) + cc * 64;
        gld_lds16(A + (size_t)(m0 + grow) * K + ecol,
                  &As[buf][cc * 8192 + (l * 512 + wid * 64) * 8]);
      } else {
        int cc = ct - 1;
        int grow = ((lr >> 5) << 6) + cc * 32 + (lr & 31);
        gld_lds16(Bm + (size_t)(n0 + grow) * K + ecol,
                  &Bs[buf][cc * 8192 + (l * 512 + wid * 64) * 8]);
      }
    }
  };
  auto rdA = [&](int buf, int mf, int kk) -> bf16x8 {
    int rl = wm2 * 64 + (mf & 3) * 16 + rr;
    return *reinterpret_cast<const bf16x8*>(
        &As[buf][(mf >> 2) * 8192 + rl * 64 + (((kk * 4 + l4) ^ (rr & 7)) * 8)]);
  };
  auto rdB = [&](int buf, int nf, int kk) -> bf16x8 {
    int rl = wn4 * 32 + (nf & 1) * 16 + rr;
    return *reinterpret_cast<const bf16x8*>(
        &Bs[buf][(nf >> 1) * 8192 + rl * 64 + (((kk * 4 + l4) ^ (rr & 7)) * 8)]);
  };

  // prologue: stage all 4 chunks of tile 0; vmcnt(4) lands ctA0,ctB0 (Ph1's reads)
  #pragma unroll
  for (int hh = 0; hh < 4; ++hh) stage(0, 0, hh);
  asm volatile("s_waitcnt vmcnt(4)" ::: "memory");
  __builtin_amdgcn_s_barrier();

  bf16x8 aF[4][2], bF[2][2], bF2[2][2];
  int cur = 0;
  for (int g2 = 0; g2 < NT; ++g2) {
    const int buf = cur, bufn = cur ^ 1;
    const int ktn = (g2 + 1 < NT) ? g2 + 1 : g2;   // last tile: harmless self re-stage
    // ---- Phase 1: Q(mf 0..3, nf 0..1); stage A0' ----
    stage(bufn, ktn, 0);
    #pragma unroll
    for (int mf = 0; mf < 4; ++mf) { aF[mf][0] = rdA(buf, mf, 0); aF[mf][1] = rdA(buf, mf, 1); }
    #pragma unroll
    for (int nf = 0; nf < 2; ++nf) { bF[nf][0] = rdB(buf, nf, 0); bF[nf][1] = rdB(buf, nf, 1); }
    __builtin_amdgcn_s_setprio(1);
    #pragma unroll
    for (int mf = 0; mf < 4; ++mf)
      #pragma unroll
      for (int nf = 0; nf < 2; ++nf) {
        acc[mf][nf] = __builtin_amdgcn_mfma_f32_16x16x32_bf16(aF[mf][0], bF[nf][0], acc[mf][nf], 0, 0, 0);
        acc[mf][nf] = __builtin_amdgcn_mfma_f32_16x16x32_bf16(aF[mf][1], bF[nf][1], acc[mf][nf], 0, 0, 0);
      }
    __builtin_amdgcn_s_setprio(0);
    asm volatile("s_waitcnt vmcnt(4)" ::: "memory");   // B1(g) landed
    __builtin_amdgcn_s_barrier();
    // ---- Phase 2: Q(mf 0..3, nf 2..3); stage B0' ----
    stage(bufn, ktn, 1);
    #pragma unroll
    for (int nf = 0; nf < 2; ++nf) { bF2[nf][0] = rdB(buf, 2 + nf, 0); bF2[nf][1] = rdB(buf, 2 + nf, 1); }
    __builtin_amdgcn_s_setprio(1);
    #pragma unroll
    for (int mf = 0; mf < 4; ++mf)
      #pragma unroll
      for (int nf = 0; nf < 2; ++nf) {
        acc[mf][2 + nf] = __builtin_amdgcn_mfma_f32_16x16x32_bf16(aF[mf][0], bF2[nf][0], acc[mf][2 + nf], 0, 0, 0);
        acc[mf][2 + nf] = __builtin_amdgcn_mfma_f32_16x16x32_bf16(aF[mf][1], bF2[nf][1], acc[mf][2 + nf], 0, 0, 0);
      }
    __builtin_amdgcn_s_setprio(0);
    asm volatile("s_waitcnt vmcnt(4)" ::: "memory");   // A1(g) landed
    __builtin_amdgcn_s_barrier();
    // ---- Phase 3: Q(mf 4..7, nf 0..1); stage B1' ----
    stage(bufn, ktn, 2);
    #pragma unroll
    for (int mf = 0; mf < 4; ++mf) { aF[mf][0] = rdA(buf, 4 + mf, 0); aF[mf][1] = rdA(buf, 4 + mf, 1); }
    __builtin_amdgcn_s_setprio(1);
    #pragma unroll
    for (int mf = 0; mf < 4; ++mf)
      #pragma unroll
      for (int nf = 0; nf < 2; ++nf) {
        acc[4 + mf][nf] = __builtin_amdgcn_mfma_f32_16x16x32_bf16(aF[mf][0], bF[nf][0], acc[4 + mf][nf], 0, 0, 0);
        acc[4 + mf][nf] = __builtin_amdgcn_mfma_f32_16x16x32_bf16(aF[mf][1], bF[nf][1], acc[4 + mf][nf], 0, 0, 0);
      }
    __builtin_amdgcn_s_setprio(0);
    // no wait, no barrier (Ph4 reads nothing new from LDS)
    // ---- Phase 4: Q(mf 4..7, nf 2..3); stage A1' ----
    stage(bufn, ktn, 3);
    __builtin_amdgcn_s_setprio(1);
    #pragma unroll
    for (int mf = 0; mf < 4; ++mf)
      #pragma unroll
      for (int nf = 0; nf < 2; ++nf) {
        acc[4 + mf][2 + nf] = __builtin_amdgcn_mfma_f32_16x16x32_bf16(aF[mf][0], bF2[nf][0], acc[4 + mf][2 + nf], 0, 0, 0);
        acc[4 + mf][2 + nf] = __builtin_amdgcn_mfma_f32_16x16x32_bf16(aF[mf][1], bF2[nf][1], acc[4 + mf][2 + nf], 0, 0, 0);
      }
    __builtin_amdgcn_s_setprio(0);
    asm volatile("s_waitcnt vmcnt(4)" ::: "memory");   // A0',B0' landed; buf free
    __builtin_amdgcn_s_barrier();
    cur ^= 1;
  }
  asm volatile("s_waitcnt vmcnt(0)" ::: "memory");

  const int vbase = m0 + wm2 * 128;
  const int nbase = n0 + wn4 * 64;
  if (MODE == 1) {
    // logits epilogue: v = vbase + mf*16 + l4*4 + r ; n=(b,t) fixed per (nf,rr)
    size_t obase[4];
    #pragma unroll
    for (int nf = 0; nf < 4; ++nf) {
      int n = nbase + nf * 16 + rr;
      int bb = n / TT, tq = n - bb * TT;
      obase[nf] = (size_t)bb * ((size_t)VV * TT) + tq;
    }
    #pragma unroll
    for (int mf = 0; mf < 8; ++mf) {
      #pragma unroll
      for (int r = 0; r < 4; ++r) {
        int v = vbase + mf * 16 + l4 * 4 + r;
        if (v < VV) {
          float bv = bias[v];
          #pragma unroll
          for (int nf = 0; nf < 4; ++nf)
            out[obase[nf] + (size_t)v * TT] = acc[mf][nf][r] + bv;
        }
      }
    }
  } else {
    // xg epilogue: m = xa-row = t*128+b ; n = gate. xgT[(m>>7)*GG + n]*BB + (m&127)
    #pragma unroll
    for (int mf = 0; mf < 8; ++mf) {
      #pragma unroll
      for (int nf = 0; nf < 4; ++nf) {
        int n = nbase + nf * 16 + rr;
        float bv = bias[n];
        #pragma unroll
        for (int r = 0; r < 4; ++r) {
          int m = vbase + mf * 16 + l4 * 4 + r;
          out[((size_t)(m >> 7) * GG + n) * BB + (m & 127)] = acc[mf][nf][r] + bv;
        }
      }
    }
  }
}

// ---------------- fused persistent LSTM (R8 group-barrier version, verbatim) ----------
__global__ __launch_bounds__(512, 1) void lstm_seq_k(
    const ushort_t* __restrict__ Whh,    // [4096][1024] bf16
    const float* __restrict__ xgT,       // [24][4096][128] f32, bias included
    ushort_t* __restrict__ hs,           // [3072][1024] bf16, row = b*24+t
    int* __restrict__ bar)               // flags[256]; rel copies at 256 + (mblk*8+c)*64
{
  __shared__ f32x4 red[6][64][4];        // 24 KB
  const int tid = threadIdx.x, wid = tid >> 6, lane = tid & 63;
  const int l16 = lane & 15, l4 = lane >> 4;
  const int bid = blockIdx.x;
  const int jblk = bid & 63, mblk = bid >> 6;
  const int j0 = jblk * 16, m0 = mblk * 32;
  const int ks = wid >> 1;
  const int msub = (wid & 1) * 16;
  int* flags = bar;
  int* rel = bar + 256;

  bf16x8 Breg[4][8];
  #pragma unroll
  for (int g = 0; g < 4; ++g) {
    const ushort_t* bp = Whh + ((size_t)(g * 1024 + j0 + l16) << 10) + ks * 256 + l4 * 8;
    #pragma unroll
    for (int kc = 0; kc < 8; ++kc)
      Breg[g][kc] = *reinterpret_cast<const bf16x8*>(bp + kc * 32);
  }
  const int arow = m0 + msub + l16;
  float c_reg[4] = {0.f, 0.f, 0.f, 0.f};

  for (int t = 0; t < TT; ++t) {
    f32x4 acc[4] = {};
    f32x4 xv[4];
    if (ks == 0) {
      const float* xp = xgT + ((size_t)(t * GG + j0 + l16)) * BB + m0 + msub + l4 * 4;
      #pragma unroll
      for (int g = 0; g < 4; ++g)
        xv[g] = *reinterpret_cast<const f32x4*>(xp + (size_t)g * 1024 * BB);
    }
    if (t > 0) {
      const u64* Ab = reinterpret_cast<const u64*>(
          hs + (((size_t)arow * TT + (t - 1)) << 10) + ks * 256 + l4 * 8);
      bf16x8 afs[8];
      #pragma unroll
      for (int kc = 0; kc < 8; ++kc) {
        union { u64 q[2]; bf16x8 v; } u;
        u.q[0] = __hip_atomic_load(Ab + kc * 8,     __ATOMIC_RELAXED, __HIP_MEMORY_SCOPE_AGENT);
        u.q[1] = __hip_atomic_load(Ab + kc * 8 + 1, __ATOMIC_RELAXED, __HIP_MEMORY_SCOPE_AGENT);
        afs[kc] = u.v;
      }
      #pragma unroll
      for (int kc = 0; kc < 8; ++kc)
        #pragma unroll
        for (int g = 0; g < 4; ++g)
          acc[g] = __builtin_amdgcn_mfma_f32_16x16x32_bf16(afs[kc], Breg[g][kc], acc[g], 0, 0, 0);
    }
    if (ks != 0) {
      int slot = (ks - 1) * 2 + (wid & 1);
      #pragma unroll
      for (int g = 0; g < 4; ++g) red[slot][lane][g] = acc[g];
    }
    __syncthreads();
    if (ks == 0) {
      #pragma unroll
      for (int s = 0; s < 3; ++s)
        #pragma unroll
        for (int g = 0; g < 4; ++g)
          acc[g] += red[s * 2 + (wid & 1)][lane][g];
      #pragma unroll
      for (int r = 0; r < 4; ++r) {
        int b = m0 + msub + l4 * 4 + r;
        float gi = acc[0][r] + xv[0][r];
        float gf = acc[1][r] + xv[1][r];
        float gg = acc[2][r] + xv[2][r];
        float go = acc[3][r] + xv[3][r];
        gi = 1.f / (1.f + expf(-gi));
        gf = 1.f / (1.f + expf(-gf));
        go = 1.f / (1.f + expf(-go));
        float cn = gf * c_reg[r] + gi * tanhf(gg);
        c_reg[r] = cn;
        float hn = go * tanhf(cn);
        unsigned hv = (unsigned)f2bf(hn);
        unsigned pv = (unsigned)__shfl_xor((int)hv, 1);
        if (!(l16 & 1)) {
          unsigned pk = (hv & 0xffffu) | (pv << 16);
          __hip_atomic_store(
              reinterpret_cast<unsigned*>(hs + (((size_t)b * TT + t) << 10) + j0 + l16),
              pk, __ATOMIC_RELAXED, __HIP_MEMORY_SCOPE_AGENT);
        }
      }
    }
    // group barrier (64 blocks sharing mblk)
    if (t < TT - 1) {
      __syncthreads();
      if (jblk == 0) {
        if (wid == 0) {
          if (lane == 0)
            __hip_atomic_store(&flags[bid], t + 1, __ATOMIC_RELAXED, __HIP_MEMORY_SCOPE_AGENT);
          for (;;) {
            int a = __hip_atomic_load(&flags[(mblk << 6) | lane], __ATOMIC_RELAXED, __HIP_MEMORY_SCOPE_AGENT);
            if (__all(a >= t + 1)) break;
            __builtin_amdgcn_s_sleep(1);
          }
          if (lane < 8)
            __hip_atomic_store(&rel[(mblk * 8 + lane) * 64], t + 1, __ATOMIC_RELAXED, __HIP_MEMORY_SCOPE_AGENT);
        }
      } else {
        if (tid == 0) {
          __hip_atomic_store(&flags[bid], t + 1, __ATOMIC_RELAXED, __HIP_MEMORY_SCOPE_AGENT);
          while (__hip_atomic_load(&rel[(mblk * 8 + (jblk & 7)) * 64], __ATOMIC_RELAXED, __HIP_MEMORY_SCOPE_AGENT) < t + 1)
            __builtin_amdgcn_s_sleep(1);
        }
      }
      __syncthreads();
    }
  }
}

// ---------------- launcher ----------------

extern "C" void kernel_launch(void* const* d_in, const int* in_sizes, int n_in,
                              void* d_out, int out_size, void* d_ws, size_t ws_size,
                              hipStream_t stream) {
  const float* features = (const float*)d_in[0];
  const int*   captions = (const int*)d_in[1];
  const int*   pad_idx  = (const int*)d_in[2];
  const float* emb      = (const float*)d_in[3];
  const float* W_ih     = (const float*)d_in[4];
  const float* W_hh     = (const float*)d_in[5];
  const float* b_ih     = (const float*)d_in[6];
  const float* b_hh     = (const float*)d_in[7];
  const float* W_out    = (const float*)d_in[8];
  const float* b_out    = (const float*)d_in[9];
  float* out = (float*)d_out;

  char* w = (char*)d_ws;
  auto carve = [&](size_t bytes) {
    char* p = w;
    w += (bytes + 255) & ~(size_t)255;
    return p;
  };
  ushort_t* Wih_b  = (ushort_t*)carve((size_t)GG * HH * 2);
  ushort_t* Whh_b  = (ushort_t*)carve((size_t)GG * HH * 2);
  ushort_t* Wout_b = (ushort_t*)carve((size_t)MPAD * HH * 2);
  ushort_t* xa     = (ushort_t*)carve((size_t)MM * HH * 2);
  float*    xgT    = (float*)carve((size_t)MM * GG * 4);        // [24][4096][128]
  ushort_t* hs     = (ushort_t*)carve((size_t)MM * HH * 2);
  float*    bsum   = (float*)carve((size_t)GG * 4);
  int*      bar    = (int*)carve(16384);

  prep_k<<<dim3(3073), 256, 0, stream>>>(W_ih, W_hh, W_out, b_ih, b_hh,
                                         Wih_b, Whh_b, Wout_b, bsum);
  build_xa_k<<<dim3(MM), 256, 0, stream>>>(emb, captions, pad_idx, features, xa);
  zero_bar_k<<<dim3(1), 256, 0, stream>>>(bar);

  // xgT: A=xa (12 m-tiles), B=Wih (16 n-tiles); grid 192 = 8 XCDs x 24 (single round)
  gemm256<0><<<dim3(192), 512, 0, stream>>>(xa, Wih_b, bsum, xgT);

  // all 24 LSTM steps in one persistent kernel
  lstm_seq_k<<<dim3(256), 512, 0, stream>>>(Whh_b, xgT, hs, bar);

  // logits: 118 x 12 tiles of 256 = 1416 = 8 x 177
  gemm256<1><<<dim3(1416), 512, 0, stream>>>(Wout_b, hs, b_out, out);
}

// Round 15
// 529.931 us; speedup vs baseline: 1.0990x; 1.0990x over previous
//
#include <hip/hip_runtime.h>
#include <hip/hip_bf16.h>
#include <math.h>

typedef unsigned short ushort_t;
typedef unsigned long long u64;
typedef __bf16 bf16x8 __attribute__((ext_vector_type(8)));
typedef float f32x4 __attribute__((ext_vector_type(4)));

#define BB 128
#define TT 24
#define EE 512
#define VV 30000
#define HH 1024
#define GG 4096
#define MM (BB*TT)   // 3072 rows, m = t*128 + b
#define MPAD 30208   // 118 tiles of 256

static __device__ __forceinline__ ushort_t f2bf(float x) {
  __hip_bfloat16 h = __float2bfloat16(x);
  return __builtin_bit_cast(ushort_t, h);
}

static __device__ __forceinline__ float fast_sigmoid(float x) {
  return __builtin_amdgcn_rcpf(1.f + __expf(-x));
}
static __device__ __forceinline__ float fast_tanh(float x) {
  return 1.f - 2.f * __builtin_amdgcn_rcpf(1.f + __expf(2.f * x));
}

// async global->LDS, 16B per lane; lds base must be wave-uniform
static __device__ __forceinline__ void gld_lds16(const void* g, void* l) {
  __builtin_amdgcn_global_load_lds((const __attribute__((address_space(1))) void*)g,
                                   (__attribute__((address_space(3))) void*)l, 16, 0, 0);
}

// ---------------- fused prep: 3 bf16 casts + bias sum ----------------
__global__ void prep_k(const float* __restrict__ Wih, const float* __restrict__ Whh,
                       const float* __restrict__ Wout,
                       const float* __restrict__ bi, const float* __restrict__ bh,
                       ushort_t* __restrict__ Wih_b, ushort_t* __restrict__ Whh_b,
                       ushort_t* __restrict__ Wout_b, float* __restrict__ bs) {
  const int bid = blockIdx.x, tid = threadIdx.x;
  const float* s; ushort_t* d; int n4, i0, stride;
  if (bid < 2048) {        // Wout: 7.68M float4
    s = Wout; d = Wout_b; n4 = VV * HH / 4; i0 = bid * 256 + tid; stride = 2048 * 256;
  } else if (bid < 2560) { // Wih
    s = Wih; d = Wih_b; n4 = GG * HH / 4; i0 = (bid - 2048) * 256 + tid; stride = 512 * 256;
  } else if (bid < 3072) { // Whh
    s = Whh; d = Whh_b; n4 = GG * HH / 4; i0 = (bid - 2560) * 256 + tid; stride = 512 * 256;
  } else {                 // bias
    for (int i = tid; i < GG; i += 256) bs[i] = bi[i] + bh[i];
    return;
  }
  for (int i = i0; i < n4; i += stride) {
    float4 v = reinterpret_cast<const float4*>(s)[i];
    ushort4 o;
    o.x = f2bf(v.x); o.y = f2bf(v.y); o.z = f2bf(v.z); o.w = f2bf(v.w);
    reinterpret_cast<ushort4*>(d)[i] = o;
  }
}

__global__ void build_xa_k(const float* __restrict__ emb, const int* __restrict__ captions,
                           const int* __restrict__ pad_idx, const float* __restrict__ features,
                           ushort_t* __restrict__ xa) {
  int row = blockIdx.x;          // 0..3071, row = t*128+b
  int t = row >> 7;
  int b = row & 127;
  int cap = (t == 0) ? pad_idx[0] : captions[b * TT + (t - 1)];
  const float* s0 = emb + (size_t)cap * EE;
  const float* s1 = features + (size_t)b * EE;
  ushort_t* d = xa + (size_t)row * (2 * EE);
  for (int e = threadIdx.x; e < EE; e += 256) {
    d[e] = f2bf(s0[e]);
    d[EE + e] = f2bf(s1[e]);
  }
}

__global__ void zero_bar_k(int* __restrict__ bar) {
  for (int i = threadIdx.x; i < 4096; i += 256)
    __hip_atomic_store(&bar[i], 0, __ATOMIC_RELAXED, __HIP_MEMORY_SCOPE_AGENT);
}

// ---------------- GEMM 256x256, deep-pipelined 4-phase/K-tile (R8-verified schedule) ----
// MODE 1 (logits): A=Wout_b[30208], B=hs[3072]; grid 1416 = 8x177, m0=(g/12)*256, n0=(g%12)*256
//                  out[b*V*T + v*T + t] + bias[v], guard v<VV.
// MODE 0 (xg):     A=xa[3072],     B=Wih_b[4096]; grid 192 = 8x24, m0=(c%12)*256,
//                  n0=(xcd*2 + c/12)*256 (Wih slice 1MB L2-resident per XCD).
//                  out = xgT[(m>>7)*4096 + n]*128 + (m&127), + bias[n].
template<int MODE>
__global__ __launch_bounds__(512) void gemm256(
    const ushort_t* __restrict__ A,
    const ushort_t* __restrict__ Bm,
    const float* __restrict__ bias,
    float* __restrict__ out)
{
  constexpr int K = 1024, NT = 16;
  __shared__ __align__(16) ushort_t As[2][16384];
  __shared__ __align__(16) ushort_t Bs[2][16384];
  const int bid = blockIdx.x;
  int m0, n0;
  if (MODE == 1) {
    const int g = (bid & 7) * 177 + (bid >> 3);     // XCD-contiguous tiles
    m0 = (g / 12) * 256; n0 = (g % 12) * 256;
  } else {
    const int c = bid >> 3;                         // 0..23
    m0 = (c % 12) * 256; n0 = ((bid & 7) * 2 + c / 12) * 256;
  }
  const int tid = threadIdx.x, wid = tid >> 6, lane = tid & 63;
  const int wm2 = wid >> 2, wn4 = wid & 3;
  const int rr = lane & 15, l4 = lane >> 4;

  f32x4 acc[8][4] = {};   // [mf 0..7][nf 0..3]

  auto stage = [&](int buf, int kt, int ct) {
    const int k0 = kt * 64;
    #pragma unroll
    for (int l = 0; l < 2; ++l) {
      int f = l * 512 + tid;
      int lr = f >> 3;
      int ecol = k0 + (((f & 7) ^ (lr & 7)) * 8);
      if (ct == 0 || ct == 3) {
        int cc = (ct == 3);
        int grow = (lr & 63) + ((lr >> 6) << 7) + cc * 64;
        gld_lds16(A + (size_t)(m0 + grow) * K + ecol,
                  &As[buf][cc * 8192 + (l * 512 + wid * 64) * 8]);
      } else {
        int cc = ct - 1;
        int grow = ((lr >> 5) << 6) + cc * 32 + (lr & 31);
        gld_lds16(Bm + (size_t)(n0 + grow) * K + ecol,
                  &Bs[buf][cc * 8192 + (l * 512 + wid * 64) * 8]);
      }
    }
  };
  auto rdA = [&](int buf, int mf, int kk) -> bf16x8 {
    int rl = wm2 * 64 + (mf & 3) * 16 + rr;
    return *reinterpret_cast<const bf16x8*>(
        &As[buf][(mf >> 2) * 8192 + rl * 64 + (((kk * 4 + l4) ^ (rr & 7)) * 8)]);
  };
  auto rdB = [&](int buf, int nf, int kk) -> bf16x8 {
    int rl = wn4 * 32 + (nf & 1) * 16 + rr;
    return *reinterpret_cast<const bf16x8*>(
        &Bs[buf][(nf >> 1) * 8192 + rl * 64 + (((kk * 4 + l4) ^ (rr & 7)) * 8)]);
  };

  // prologue: stage all 4 chunks of tile 0; vmcnt(4) lands ctA0,ctB0 (Ph1's reads)
  #pragma unroll
  for (int hh = 0; hh < 4; ++hh) stage(0, 0, hh);
  asm volatile("s_waitcnt vmcnt(4)" ::: "memory");
  __builtin_amdgcn_s_barrier();

  bf16x8 aF[4][2], bF[2][2], bF2[2][2];
  int cur = 0;
  for (int g2 = 0; g2 < NT; ++g2) {
    const int buf = cur, bufn = cur ^ 1;
    const int ktn = (g2 + 1 < NT) ? g2 + 1 : g2;   // last tile: harmless self re-stage
    // ---------------- Phase 1: Q(mf 0..3, nf 0..1) ----------------
    #pragma unroll
    for (int mf = 0; mf < 4; ++mf) { aF[mf][0] = rdA(buf, mf, 0); aF[mf][1] = rdA(buf, mf, 1); }
    #pragma unroll
    for (int nf = 0; nf < 2; ++nf) { bF[nf][0] = rdB(buf, nf, 0); bF[nf][1] = rdB(buf, nf, 1); }
    stage(bufn, ktn, 0);
    __builtin_amdgcn_s_barrier();
    asm volatile("s_waitcnt lgkmcnt(0)" ::: "memory");
    __builtin_amdgcn_sched_barrier(0);
    __builtin_amdgcn_s_setprio(1);
    #pragma unroll
    for (int mf = 0; mf < 4; ++mf)
      #pragma unroll
      for (int nf = 0; nf < 2; ++nf) {
        acc[mf][nf] = __builtin_amdgcn_mfma_f32_16x16x32_bf16(aF[mf][0], bF[nf][0], acc[mf][nf], 0, 0, 0);
        acc[mf][nf] = __builtin_amdgcn_mfma_f32_16x16x32_bf16(aF[mf][1], bF[nf][1], acc[mf][nf], 0, 0, 0);
      }
    __builtin_amdgcn_s_setprio(0);
    asm volatile("s_waitcnt vmcnt(4)" ::: "memory");
    __builtin_amdgcn_s_barrier();
    // ---------------- Phase 2: Q(mf 0..3, nf 2..3) ----------------
    #pragma unroll
    for (int nf = 0; nf < 2; ++nf) { bF2[nf][0] = rdB(buf, 2 + nf, 0); bF2[nf][1] = rdB(buf, 2 + nf, 1); }
    stage(bufn, ktn, 1);
    __builtin_amdgcn_s_barrier();
    asm volatile("s_waitcnt lgkmcnt(0)" ::: "memory");
    __builtin_amdgcn_sched_barrier(0);
    __builtin_amdgcn_s_setprio(1);
    #pragma unroll
    for (int mf = 0; mf < 4; ++mf)
      #pragma unroll
      for (int nf = 0; nf < 2; ++nf) {
        acc[mf][2 + nf] = __builtin_amdgcn_mfma_f32_16x16x32_bf16(aF[mf][0], bF2[nf][0], acc[mf][2 + nf], 0, 0, 0);
        acc[mf][2 + nf] = __builtin_amdgcn_mfma_f32_16x16x32_bf16(aF[mf][1], bF2[nf][1], acc[mf][2 + nf], 0, 0, 0);
      }
    __builtin_amdgcn_s_setprio(0);
    asm volatile("s_waitcnt vmcnt(4)" ::: "memory");
    __builtin_amdgcn_s_barrier();
    // ---------------- Phase 3: Q(mf 4..7, nf 0..1) ----------------
    #pragma unroll
    for (int mf = 0; mf < 4; ++mf) { aF[mf][0] = rdA(buf, 4 + mf, 0); aF[mf][1] = rdA(buf, 4 + mf, 1); }
    stage(bufn, ktn, 2);
    __builtin_amdgcn_s_barrier();
    asm volatile("s_waitcnt lgkmcnt(0)" ::: "memory");
    __builtin_amdgcn_sched_barrier(0);
    __builtin_amdgcn_s_setprio(1);
    #pragma unroll
    for (int mf = 0; mf < 4; ++mf)
      #pragma unroll
      for (int nf = 0; nf < 2; ++nf) {
        acc[4 + mf][nf] = __builtin_amdgcn_mfma_f32_16x16x32_bf16(aF[mf][0], bF[nf][0], acc[4 + mf][nf], 0, 0, 0);
        acc[4 + mf][nf] = __builtin_amdgcn_mfma_f32_16x16x32_bf16(aF[mf][1], bF[nf][1], acc[4 + mf][nf], 0, 0, 0);
      }
    __builtin_amdgcn_s_setprio(0);
    __builtin_amdgcn_s_barrier();
    // ---------------- Phase 4: Q(mf 4..7, nf 2..3) ----------------
    stage(bufn, ktn, 3);
    __builtin_amdgcn_s_barrier();
    __builtin_amdgcn_s_setprio(1);
    #pragma unroll
    for (int mf = 0; mf < 4; ++mf)
      #pragma unroll
      for (int nf = 0; nf < 2; ++nf) {
        acc[4 + mf][2 + nf] = __builtin_amdgcn_mfma_f32_16x16x32_bf16(aF[mf][0], bF2[nf][0], acc[4 + mf][2 + nf], 0, 0, 0);
        acc[4 + mf][2 + nf] = __builtin_amdgcn_mfma_f32_16x16x32_bf16(aF[mf][1], bF2[nf][1], acc[4 + mf][2 + nf], 0, 0, 0);
      }
    __builtin_amdgcn_s_setprio(0);
    asm volatile("s_waitcnt vmcnt(4)" ::: "memory");
    __builtin_amdgcn_s_barrier();
    cur ^= 1;
  }
  asm volatile("s_waitcnt vmcnt(0)" ::: "memory");

  const int vbase = m0 + wm2 * 128;
  const int nbase = n0 + wn4 * 64;
  if (MODE == 1) {
    // logits epilogue: v = vbase + mf*16 + l4*4 + r ; n=(b,t) fixed per (nf,rr)
    size_t obase[4];
    #pragma unroll
    for (int nf = 0; nf < 4; ++nf) {
      int n = nbase + nf * 16 + rr;
      int bb = n / TT, tq = n - bb * TT;
      obase[nf] = (size_t)bb * ((size_t)VV * TT) + tq;
    }
    #pragma unroll
    for (int mf = 0; mf < 8; ++mf) {
      #pragma unroll
      for (int r = 0; r < 4; ++r) {
        int v = vbase + mf * 16 + l4 * 4 + r;
        if (v < VV) {
          float bv = bias[v];
          #pragma unroll
          for (int nf = 0; nf < 4; ++nf)
            out[obase[nf] + (size_t)v * TT] = acc[mf][nf][r] + bv;
        }
      }
    }
  } else {
    // xg epilogue: m = xa-row = t*128+b ; n = gate. xgT[(m>>7)*GG + n]*BB + (m&127)
    #pragma unroll
    for (int mf = 0; mf < 8; ++mf) {
      #pragma unroll
      for (int nf = 0; nf < 4; ++nf) {
        int n = nbase + nf * 16 + rr;
        float bv = bias[n];
        #pragma unroll
        for (int r = 0; r < 4; ++r) {
          int m = vbase + mf * 16 + l4 * 4 + r;
          out[((size_t)(m >> 7) * GG + n) * BB + (m & 127)] = acc[mf][nf][r] + bv;
        }
      }
    }
  }
}

// ---------------- fused persistent LSTM (R8 group-barrier version) ----------
__global__ __launch_bounds__(512, 1) void lstm_seq_k(
    const ushort_t* __restrict__ Whh,    // [4096][1024] bf16
    const float* __restrict__ xgT,       // [24][4096][128] f32, bias included
    ushort_t* __restrict__ hs,           // [3072][1024] bf16, row = b*24+t
    int* __restrict__ bar)               // flags[256]; rel copies at 256 + (mblk*8+c)*64
{
  __shared__ f32x4 red[6][64][4];        // 24 KB
  const int tid = threadIdx.x, wid = tid >> 6, lane = tid & 63;
  const int l16 = lane & 15, l4 = lane >> 4;
  const int bid = blockIdx.x;
  const int jblk = bid & 63, mblk = bid >> 6;
  const int j0 = jblk * 16, m0 = mblk * 32;
  const int ks = wid >> 1;
  const int msub = (wid & 1) * 16;
  int* flags = bar;
  int* rel = bar + 256;

  bf16x8 Breg[4][8];
  #pragma unroll
  for (int g = 0; g < 4; ++g) {
    const ushort_t* bp = Whh + ((size_t)(g * 1024 + j0 + l16) << 10) + ks * 256 + l4 * 8;
    #pragma unroll
    for (int kc = 0; kc < 8; ++kc)
      Breg[g][kc] = *reinterpret_cast<const bf16x8*>(bp + kc * 32);
  }
  const int arow = m0 + msub + l16;
  float c_reg[4] = {0.f, 0.f, 0.f, 0.f};

  for (int t = 0; t < TT; ++t) {
    f32x4 acc[4] = {};
    f32x4 xv[4];
    if (ks == 0) {
      const float* xp = xgT + ((size_t)(t * GG + j0 + l16)) * BB + m0 + msub + l4 * 4;
      #pragma unroll
      for (int g = 0; g < 4; ++g)
        xv[g] = *reinterpret_cast<const f32x4*>(xp + (size_t)g * 1024 * BB);
    }
    if (t > 0) {
      const u64* Ab = reinterpret_cast<const u64*>(
          hs + (((size_t)arow * TT + (t - 1)) << 10) + ks * 256 + l4 * 8);
      bf16x8 afs[8];
      #pragma unroll
      for (int kc = 0; kc < 8; ++kc) {
        union { u64 q[2]; bf16x8 v; } u;
        u.q[0] = __hip_atomic_load(Ab + kc * 8,     __ATOMIC_RELAXED, __HIP_MEMORY_SCOPE_AGENT);
        u.q[1] = __hip_atomic_load(Ab + kc * 8 + 1, __ATOMIC_RELAXED, __HIP_MEMORY_SCOPE_AGENT);
        afs[kc] = u.v;
      }
      #pragma unroll
      for (int kc = 0; kc < 8; ++kc)
        #pragma unroll
        for (int g = 0; g < 4; ++g)
          acc[g] = __builtin_amdgcn_mfma_f32_16x16x32_bf16(afs[kc], Breg[g][kc], acc[g], 0, 0, 0);
    }
    if (ks != 0) {
      int slot = (ks - 1) * 2 + (wid & 1);
      #pragma unroll
      for (int g = 0; g < 4; ++g) red[slot][lane][g] = acc[g];
    }
    __syncthreads();
    if (ks == 0) {
      #pragma unroll
      for (int s = 0; s < 3; ++s)
        #pragma unroll
        for (int g = 0; g < 4; ++g)
          acc[g] += red[s * 2 + (wid & 1)][lane][g];
      #pragma unroll
      for (int r = 0; r < 4; ++r) {
        int b = m0 + msub + l4 * 4 + r;
        float gi = fast_sigmoid(acc[0][r] + xv[0][r]);
        float gf = fast_sigmoid(acc[1][r] + xv[1][r]);
        float tg = fast_tanh(acc[2][r] + xv[2][r]);
        float go = fast_sigmoid(acc[3][r] + xv[3][r]);
        float cn = gf * c_reg[r] + gi * tg;
        c_reg[r] = cn;
        float hn = go * fast_tanh(cn);
        unsigned hv = (unsigned)f2bf(hn);
        unsigned pv = (unsigned)__shfl_xor((int)hv, 1);
        if (!(l16 & 1)) {
          unsigned pk = (hv & 0xffffu) | (pv << 16);
          __hip_atomic_store(
              reinterpret_cast<unsigned*>(hs + (((size_t)b * TT + t) << 10) + j0 + l16),
              pk, __ATOMIC_RELAXED, __HIP_MEMORY_SCOPE_AGENT);
        }
      }
    }
    // group barrier (64 blocks sharing mblk)
    if (t < TT - 1) {
      __syncthreads();
      if (jblk == 0) {
        if (wid == 0) {
          if (lane == 0)
            __hip_atomic_store(&flags[bid], t + 1, __ATOMIC_RELAXED, __HIP_MEMORY_SCOPE_AGENT);
          for (;;) {
            int a = __hip_atomic_load(&flags[(mblk << 6) | lane], __ATOMIC_RELAXED, __HIP_MEMORY_SCOPE_AGENT);
            if (__all(a >= t + 1)) break;
            __builtin_amdgcn_s_sleep(1);
          }
          if (lane < 8)
            __hip_atomic_store(&rel[(mblk * 8 + lane) * 64], t + 1, __ATOMIC_RELAXED, __HIP_MEMORY_SCOPE_AGENT);
        }
      } else {
        if (tid == 0) {
          __hip_atomic_store(&flags[bid], t + 1, __ATOMIC_RELAXED, __HIP_MEMORY_SCOPE_AGENT);
          while (__hip_atomic_load(&rel[(mblk * 8 + (jblk & 7)) * 64], __ATOMIC_RELAXED, __HIP_MEMORY_SCOPE_AGENT) < t + 1)
            __builtin_amdgcn_s_sleep(1);
        }
      }
      __syncthreads();
    }
  }
}

// ---------------- launcher ----------------

extern "C" void kernel_launch(void* const* d_in, const int* in_sizes, int n_in,
                              void* d_out, int out_size, void* d_ws, size_t ws_size,
                              hipStream_t stream) {
  const float* features = (const float*)d_in[0];
  const int*   captions = (const int*)d_in[1];
  const int*   pad_idx  = (const int*)d_in[2];
  const float* emb      = (const float*)d_in[3];
  const float* W_ih     = (const float*)d_in[4];
  const float* W_hh     = (const float*)d_in[5];
  const float* b_ih     = (const float*)d_in[6];
  const float* b_hh     = (const float*)d_in[7];
  const float* W_out    = (const float*)d_in[8];
  const float* b_out    = (const float*)d_in[9];
  float* out = (float*)d_out;

  char* w = (char*)d_ws;
  auto carve = [&](size_t bytes) {
    char* p = w;
    w += (bytes + 255) & ~(size_t)255;
    return p;
  };
  ushort_t* Wih_b  = (ushort_t*)carve((size_t)GG * HH * 2);
  ushort_t* Whh_b  = (ushort_t*)carve((size_t)GG * HH * 2);
  ushort_t* Wout_b = (ushort_t*)carve((size_t)MPAD * HH * 2);
  ushort_t* xa     = (ushort_t*)carve((size_t)MM * HH * 2);
  float*    xgT    = (float*)carve((size_t)MM * GG * 4);        // [24][4096][128]
  ushort_t* hs     = (ushort_t*)carve((size_t)MM * HH * 2);
  float*    bsum   = (float*)carve((size_t)GG * 4);
  int*      bar    = (int*)carve(16384);

  prep_k<<<dim3(3073), 256, 0, stream>>>(W_ih, W_hh, W_out, b_ih, b_hh,
                                         Wih_b, Whh_b, Wout_b, bsum);
  build_xa_k<<<dim3(MM), 256, 0, stream>>>(emb, captions, pad_idx, features, xa);
  zero_bar_k<<<dim3(1), 256, 0, stream>>>(bar);

  // xgT: A=xa (12 m-tiles), B=Wih (16 n-tiles); grid 192 = 8 XCDs x 24 (single round)
  gemm256<0><<<dim3(192), 512, 0, stream>>>(xa, Wih_b, bsum, xgT);

  // all 24 LSTM steps in one persistent kernel
  lstm_seq_k<<<dim3(256), 512, 0, stream>>>(Whh_b, xgT, hs, bar);

  // logits: 118 x 12 tiles of 256 = 1416 = 8 x 177
  gemm256<1><<<dim3(1416), 512, 0, stream>>>(Wout_b, hs, b_out, out);
}